// Round 8
// baseline (746.993 us; speedup 1.0000x reference)
//
#include <hip/hip_runtime.h>

// TurboFlashAttention: causal B=2,H=16,S=2048,D=64 fp32 + 512MB zero placeholder.
// R8 (= R7 with __fp16 types): BARRIER-FREE flash loop. K frags direct from
// global (L1-shared across the block's 4 waves), V^T frags via stride-64 scalar
// loads, f16 MFMA via v_cvt_pkrtz (1 inst / 2 elts), P^T transpose in
// wave-private LDS (lgkm only). Zero __syncthreads => no vmcnt(0) convoy;
// 8 independent waves/CU hide latency. Fused uniform zero-fill (1MB/block).

typedef __fp16 f16x2 __attribute__((ext_vector_type(2)));
typedef __fp16 f16x4 __attribute__((ext_vector_type(4)));
typedef __fp16 f16x8 __attribute__((ext_vector_type(8)));
typedef float f32x4 __attribute__((ext_vector_type(4)));

#define LOG2E 1.44269504088896340736f

constexpr int Sdim = 2048, Ddim = 64, BHn = 32;
constexpr int STiles = 16;                   // 128-row q-supertiles
constexpr int LDK = 72;                      // Plds leading-dim pad (f16 units)
constexpr int OUT0 = BHn * Sdim * Ddim;      // output-region floats

__device__ __forceinline__ f16x8 cvt8(float4 a, float4 b) {
  union { f16x2 h2[4]; f16x8 v; } u;
  u.h2[0] = __builtin_amdgcn_cvt_pkrtz(a.x, a.y);
  u.h2[1] = __builtin_amdgcn_cvt_pkrtz(a.z, a.w);
  u.h2[2] = __builtin_amdgcn_cvt_pkrtz(b.x, b.y);
  u.h2[3] = __builtin_amdgcn_cvt_pkrtz(b.z, b.w);
  return u.v;
}

__global__ __launch_bounds__(256, 2)
void flash_causal_kernel(const float* __restrict__ Q, const float* __restrict__ K,
                         const float* __restrict__ V, float* __restrict__ out) {
  __shared__ __fp16 Plds[4][2][16 * LDK];   // wave-private P^T round-trip

  const int tid  = threadIdx.x;
  const int wave = tid >> 6;
  const int lane = tid & 63;
  const int quad = lane >> 4;
  const int l15  = lane & 15;

  const int bh = blockIdx.x & (BHn - 1);
  const int s  = (int)(blockIdx.x >> 5);      // 0..15 (all 512 blocks co-resident)
  const int jmax = 2 * s + 1;

  const int base  = bh * Sdim * Ddim;
  const int qbase = s * 128;

  // ---- Q fragments (B-operand: n=l15=qm, k=8*quad+j), scale 1/8 folded.
  f16x8 aq[2][2];
  #pragma unroll
  for (int f = 0; f < 2; ++f) {
    #pragma unroll
    for (int s2 = 0; s2 < 2; ++s2) {
      const float* qp = Q + base + (qbase + 64 * f + wave * 16 + l15) * Ddim
                          + 32 * s2 + 8 * quad;
      float4 a = *(const float4*)qp;
      float4 b = *(const float4*)(qp + 4);
      float4 as, bs;
      as.x = a.x * 0.125f; as.y = a.y * 0.125f; as.z = a.z * 0.125f; as.w = a.w * 0.125f;
      bs.x = b.x * 0.125f; bs.y = b.y * 0.125f; bs.z = b.z * 0.125f; bs.w = b.w * 0.125f;
      aq[f][s2] = cvt8(as, bs);
    }
  }

  f32x4 ot[2][4];                              // O^T rows d=16t+4q+r, col qm=l15
  #pragma unroll
  for (int f = 0; f < 2; ++f)
    #pragma unroll
    for (int t = 0; t < 4; ++t) ot[f][t] = (f32x4){0.f, 0.f, 0.f, 0.f};
  float mrun[2] = {-__builtin_inff(), -__builtin_inff()};
  float lrun[2] = {0.f, 0.f};

  for (int j = 0; j <= jmax; ++j) {
    const float* kb = K + base + (64 * j) * Ddim;
    const float* vb = V + base + (64 * j) * Ddim;
    const bool f0act = (j <= 2 * s);

    // ---- S^T = K * Q^T. A-frag (t,s2) is 2 contiguous float4 from global K;
    // all 4 waves read the same 16KB tile -> L1-shared.
    f32x4 sc[2][4];
    #pragma unroll
    for (int f = 0; f < 2; ++f)
      #pragma unroll
      for (int t = 0; t < 4; ++t) sc[f][t] = (f32x4){0.f, 0.f, 0.f, 0.f};
    #pragma unroll
    for (int s2 = 0; s2 < 2; ++s2) {
      #pragma unroll
      for (int t = 0; t < 4; ++t) {
        const float* kp = kb + (16 * t + l15) * Ddim + 32 * s2 + 8 * quad;
        float4 a = *(const float4*)kp;
        float4 b = *(const float4*)(kp + 4);
        f16x8 ka = cvt8(a, b);
        sc[0][t] = __builtin_amdgcn_mfma_f32_16x16x32_f16(ka, aq[0][s2], sc[0][t], 0, 0, 0);
        sc[1][t] = __builtin_amdgcn_mfma_f32_16x16x32_f16(ka, aq[1][s2], sc[1][t], 0, 0, 0);
      }
    }

    // ---- causal diagonal mask (frag f diag at j == 2s+f; local coords equal)
    #pragma unroll
    for (int f = 0; f < 2; ++f) {
      if (j == 2 * s + f) {
        const int qml = wave * 16 + l15;
        #pragma unroll
        for (int t = 0; t < 4; ++t)
          #pragma unroll
          for (int r = 0; r < 4; ++r)
            if (16 * t + 4 * quad + r > qml) sc[f][t][r] = -__builtin_inff();
      }
    }

    // ---- online softmax (row qm=l15 per-lane; 2 cross-quad shuffles) + P^T write
    #pragma unroll
    for (int f = 0; f < 2; ++f) {
      if (f == 0 && !f0act) continue;
      float mx = sc[f][0][0];
      #pragma unroll
      for (int t = 0; t < 4; ++t)
        #pragma unroll
        for (int r = 0; r < 4; ++r) mx = fmaxf(mx, sc[f][t][r]);
      mx = fmaxf(mx, __shfl_xor(mx, 16));
      mx = fmaxf(mx, __shfl_xor(mx, 32));
      float mn    = fmaxf(mrun[f], mx);
      float alpha = __builtin_amdgcn_exp2f((mrun[f] - mn) * LOG2E);
      float msc   = mn * LOG2E;
      mrun[f] = mn;
      float rs = 0.f;
      #pragma unroll
      for (int t = 0; t < 4; ++t)
        #pragma unroll
        for (int r = 0; r < 4; ++r) {
          float p = __builtin_amdgcn_exp2f(fmaf(sc[f][t][r], LOG2E, -msc));
          sc[f][t][r] = p;
          rs += p;
        }
      rs += __shfl_xor(rs, 16);
      rs += __shfl_xor(rs, 32);
      lrun[f] = lrun[f] * alpha + rs;
      #pragma unroll
      for (int t = 0; t < 4; ++t)
        #pragma unroll
        for (int r = 0; r < 4; ++r) ot[f][t][r] *= alpha;
      #pragma unroll
      for (int t = 0; t < 4; ++t) {
        union { f16x2 h2[2]; f16x4 v; } pu;
        pu.h2[0] = __builtin_amdgcn_cvt_pkrtz(sc[f][t][0], sc[f][t][1]);
        pu.h2[1] = __builtin_amdgcn_cvt_pkrtz(sc[f][t][2], sc[f][t][3]);
        *(f16x4*)&Plds[wave][f][l15 * LDK + 16 * t + 4 * quad] = pu.v;
      }
    }

    // ---- O^T += V^T * P^T. V^T A-frag via stride-64 scalar loads (L1/L2-hit);
    // P^T B-frag read back from wave-private LDS (lgkmcnt ordering only).
    #pragma unroll
    for (int s2 = 0; s2 < 2; ++s2) {
      f16x8 pb0, pb1;
      if (f0act) pb0 = *(const f16x8*)&Plds[wave][0][l15 * LDK + 32 * s2 + 8 * quad];
      pb1 = *(const f16x8*)&Plds[wave][1][l15 * LDK + 32 * s2 + 8 * quad];
      const float* vp = vb + (32 * s2 + 8 * quad) * Ddim + l15;
      #pragma unroll
      for (int t = 0; t < 4; ++t) {
        float4 a, b;
        const float* vt = vp + 16 * t;
        a.x = vt[0];        a.y = vt[Ddim];     a.z = vt[2 * Ddim]; a.w = vt[3 * Ddim];
        b.x = vt[4 * Ddim]; b.y = vt[5 * Ddim]; b.z = vt[6 * Ddim]; b.w = vt[7 * Ddim];
        f16x8 va = cvt8(a, b);
        if (f0act)
          ot[0][t] = __builtin_amdgcn_mfma_f32_16x16x32_f16(va, pb0, ot[0][t], 0, 0, 0);
        ot[1][t] = __builtin_amdgcn_mfma_f32_16x16x32_f16(va, pb1, ot[1][t], 0, 0, 0);
      }
    }
  }

  // ---- epilogue: O[qm][d] = O^T / l — one float4 store per (f,t)
  #pragma unroll
  for (int f = 0; f < 2; ++f) {
    float inv = 1.0f / lrun[f];
    float* orow = out + base + (qbase + 64 * f + wave * 16 + l15) * Ddim + 4 * quad;
    #pragma unroll
    for (int t = 0; t < 4; ++t) {
      f32x4 o4;
      o4.x = ot[f][t][0] * inv; o4.y = ot[f][t][1] * inv;
      o4.z = ot[f][t][2] * inv; o4.w = ot[f][t][3] * inv;
      *(f32x4*)(orow + 16 * t) = o4;
    }
  }

  // ---- uniform zero-fill of the placeholder: 1MB per block, plain stores.
  {
    f32x4 z4 = (f32x4){0.f, 0.f, 0.f, 0.f};
    f32x4* zp = (f32x4*)(out + OUT0) + (size_t)blockIdx.x * 65536 + tid;
    #pragma unroll 8
    for (int i = 0; i < 256; ++i)
      zp[i * 256] = z4;
  }
}

extern "C" void kernel_launch(void* const* d_in, const int* in_sizes, int n_in,
                              void* d_out, int out_size, void* d_ws, size_t ws_size,
                              hipStream_t stream) {
  const float* q = (const float*)d_in[0];
  const float* k = (const float*)d_in[1];
  const float* v = (const float*)d_in[2];
  float* out = (float*)d_out;
  dim3 grid(BHn * STiles);   // 512 blocks, all co-resident (2 per CU)
  flash_causal_kernel<<<grid, dim3(256), 0, stream>>>(q, k, v, out);
}

// Round 9
// 606.521 us; speedup vs baseline: 1.2316x; 1.2316x over previous
//
#include <hip/hip_runtime.h>

// TurboFlashAttention: causal B=2,H=16,S=2048,D=64 fp32 + 512MB zero placeholder.
// R9: R6 flash core (dbuf LDS, 1 barrier/iter, swizzled V^T, balanced CU pairs)
// + zero-fill INTERLEAVED into the K-loop (32KB/iter/block, remainder post-loop)
// so placeholder stores hide in the flash loop's idle memory slots.

typedef __bf16 bf16x8 __attribute__((ext_vector_type(8)));
typedef float f32x4 __attribute__((ext_vector_type(4)));

#define LOG2E 1.44269504088896340736f

__device__ __forceinline__ unsigned short f2bf(float f) {
  unsigned int u = __float_as_uint(f);
  u += 0x7fffu + ((u >> 16) & 1u);   // RNE
  return (unsigned short)(u >> 16);
}

constexpr int Sdim = 2048, Ddim = 64, BHn = 32;
constexpr int STiles = 16;                   // 128-row q-supertiles
constexpr int LDK = 72;                      // LDS leading-dim pad (shorts)
constexpr int OUT0 = BHn * Sdim * Ddim;      // output-region floats
constexpr int FCHUNK = 2048;                 // f32x4 per fill chunk (32KB)
constexpr int NCHUNK = 32;                   // chunks per block (1MB total)

__device__ __forceinline__ int vswz_m(int d) { return ((d >> 2) ^ (d >> 5)) & 7; }

__global__ __launch_bounds__(256, 2)
void flash_causal_kernel(const float* __restrict__ Q, const float* __restrict__ K,
                         const float* __restrict__ V, float* __restrict__ out) {
  __shared__ unsigned short Klds[2][64 * LDK];      // K tile [kn][d]
  __shared__ unsigned short Vlds[2][64 * LDK];      // V^T tile [d][kn^swz]
  __shared__ unsigned short Plds[4][2][16 * LDK];   // per-wave, per-frag P^T

  const int tid  = threadIdx.x;
  const int wave = tid >> 6;
  const int lane = tid & 63;
  const int quad = lane >> 4;
  const int l15  = lane & 15;

  const int bh = blockIdx.x & (BHn - 1);
  const int g  = (int)(blockIdx.x >> 5);                 // 0..15
  // Blocks i and i+256 co-resident on one CU -> pair (g, g+8): s-pair sums 15
  // (iteration counts sum to 34) for uniform per-CU compute load.
  const int s  = (g < 8) ? g : (23 - g);
  const int jmax = 2 * s + 1;

  const int base  = bh * Sdim * Ddim;
  const int qbase = s * 128;

  // fill region for this block: 1MB, stored as 32 chunks of 32KB
  f32x4* zbase = (f32x4*)(out + OUT0) + (size_t)blockIdx.x * (FCHUNK * NCHUNK);
  const f32x4 z4 = (f32x4){0.f, 0.f, 0.f, 0.f};

  // ---- Q fragments (B-operand), scale 1/8 folded. frag f: rows qbase+64f+16w.
  bf16x8 aq[2][2];
  #pragma unroll
  for (int f = 0; f < 2; ++f) {
    const float* qp = Q + base + (qbase + 64 * f + wave * 16 + l15) * Ddim + quad * 8;
    #pragma unroll
    for (int s2 = 0; s2 < 2; ++s2) {
      float4 a = *(const float4*)(qp + 32 * s2);
      float4 b = *(const float4*)(qp + 32 * s2 + 4);
      union { unsigned short u[8]; bf16x8 v; } u;
      u.u[0] = f2bf(a.x * 0.125f); u.u[1] = f2bf(a.y * 0.125f);
      u.u[2] = f2bf(a.z * 0.125f); u.u[3] = f2bf(a.w * 0.125f);
      u.u[4] = f2bf(b.x * 0.125f); u.u[5] = f2bf(b.y * 0.125f);
      u.u[6] = f2bf(b.z * 0.125f); u.u[7] = f2bf(b.w * 0.125f);
      aq[f][s2] = u.v;
    }
  }

  f32x4 ot[2][4];
  #pragma unroll
  for (int f = 0; f < 2; ++f)
    #pragma unroll
    for (int t = 0; t < 4; ++t) ot[f][t] = (f32x4){0.f, 0.f, 0.f, 0.f};
  float mrun[2] = {-__builtin_inff(), -__builtin_inff()};
  float lrun[2] = {0.f, 0.f};

  const float4* kg4 = (const float4*)(K + base);
  const float4* vg4 = (const float4*)(V + base);
  float4 kf[4], vf[4];

  auto ldtile = [&](int j) {
    const float4* kp = kg4 + j * 1024;
    const float4* vp = vg4 + j * 1024;
    #pragma unroll
    for (int i = 0; i < 4; ++i) { kf[i] = kp[i * 256 + tid]; vf[i] = vp[i * 256 + tid]; }
  };
  auto stage = [&](int buf) {
    #pragma unroll
    for (int i = 0; i < 4; ++i) {
      int lin = i * 256 + tid;
      int row = lin >> 4;
      int c4  = (lin & 15) << 2;
      uint2 t2;
      t2.x = (unsigned int)f2bf(kf[i].x) | ((unsigned int)f2bf(kf[i].y) << 16);
      t2.y = (unsigned int)f2bf(kf[i].z) | ((unsigned int)f2bf(kf[i].w) << 16);
      *(uint2*)&Klds[buf][row * LDK + c4] = t2;
      const int sw = vswz_m(c4) << 3;
      Vlds[buf][(c4 + 0) * LDK + (row ^ sw)] = f2bf(vf[i].x);
      Vlds[buf][(c4 + 1) * LDK + (row ^ sw)] = f2bf(vf[i].y);
      Vlds[buf][(c4 + 2) * LDK + (row ^ sw)] = f2bf(vf[i].z);
      Vlds[buf][(c4 + 3) * LDK + (row ^ sw)] = f2bf(vf[i].w);
    }
  };

  // ---- prologue
  ldtile(0); stage(0); ldtile(1);   // jmax >= 1 always

  for (int j = 0; j <= jmax; ++j) {
    __syncthreads();
    if (j < jmax) stage((j + 1) & 1);
    if (j + 2 <= jmax) ldtile(j + 2);

    // ---- interleaved zero-fill: one 32KB chunk per iteration, fire-and-forget
    if (j < NCHUNK) {
      f32x4* zp = zbase + j * FCHUNK + tid;
      #pragma unroll
      for (int i = 0; i < FCHUNK / 256; ++i)
        __builtin_nontemporal_store(z4, zp + i * 256);
    }

    const unsigned short* Kb = Klds[j & 1];
    const unsigned short* Vb = Vlds[j & 1];
    const bool f0act = (j <= 2 * s);   // frag0 has no columns at j == jmax

    // ---- S^T for both frags; K fragment read once, used twice
    f32x4 sc[2][4];
    #pragma unroll
    for (int f = 0; f < 2; ++f)
      #pragma unroll
      for (int t = 0; t < 4; ++t) sc[f][t] = (f32x4){0.f, 0.f, 0.f, 0.f};
    #pragma unroll
    for (int s2 = 0; s2 < 2; ++s2) {
      #pragma unroll
      for (int t = 0; t < 4; ++t) {
        bf16x8 ka = *(const bf16x8*)&Kb[(16 * t + l15) * LDK + 32 * s2 + quad * 8];
        sc[0][t] = __builtin_amdgcn_mfma_f32_16x16x32_bf16(ka, aq[0][s2], sc[0][t], 0, 0, 0);
        sc[1][t] = __builtin_amdgcn_mfma_f32_16x16x32_bf16(ka, aq[1][s2], sc[1][t], 0, 0, 0);
      }
    }

    // ---- causal diagonal masks (frag f diag at j == 2s+f)
    #pragma unroll
    for (int f = 0; f < 2; ++f) {
      if (j == 2 * s + f) {
        const int qml = wave * 16 + l15;
        #pragma unroll
        for (int t = 0; t < 4; ++t)
          #pragma unroll
          for (int r = 0; r < 4; ++r)
            if (16 * t + 4 * quad + r > qml) sc[f][t][r] = -__builtin_inff();
      }
    }

    // ---- online softmax + P write (per frag; frag0 idle on final odd iter)
    #pragma unroll
    for (int f = 0; f < 2; ++f) {
      if (f == 0 && !f0act) continue;
      float mx = sc[f][0][0];
      #pragma unroll
      for (int t = 0; t < 4; ++t)
        #pragma unroll
        for (int r = 0; r < 4; ++r) mx = fmaxf(mx, sc[f][t][r]);
      mx = fmaxf(mx, __shfl_xor(mx, 16));
      mx = fmaxf(mx, __shfl_xor(mx, 32));
      float mn    = fmaxf(mrun[f], mx);
      float alpha = __builtin_amdgcn_exp2f((mrun[f] - mn) * LOG2E);
      float msc   = mn * LOG2E;
      mrun[f] = mn;
      float rs = 0.f;
      #pragma unroll
      for (int t = 0; t < 4; ++t)
        #pragma unroll
        for (int r = 0; r < 4; ++r) {
          float p = __builtin_amdgcn_exp2f(fmaf(sc[f][t][r], LOG2E, -msc));
          sc[f][t][r] = p;
          rs += p;
        }
      rs += __shfl_xor(rs, 16);
      rs += __shfl_xor(rs, 32);
      lrun[f] = lrun[f] * alpha + rs;
      #pragma unroll
      for (int t = 0; t < 4; ++t)
        #pragma unroll
        for (int r = 0; r < 4; ++r) ot[f][t][r] *= alpha;
      #pragma unroll
      for (int t = 0; t < 4; ++t) {
        uint2 pw;
        pw.x = (unsigned int)f2bf(sc[f][t][0]) | ((unsigned int)f2bf(sc[f][t][1]) << 16);
        pw.y = (unsigned int)f2bf(sc[f][t][2]) | ((unsigned int)f2bf(sc[f][t][3]) << 16);
        *(uint2*)&Plds[wave][f][l15 * LDK + 16 * t + 4 * quad] = pw;
      }
    }

    // ---- O^T += V^T * P^T; V fragment read once, used for both frags
    #pragma unroll
    for (int s2 = 0; s2 < 2; ++s2) {
      bf16x8 pb0, pb1;
      if (f0act) pb0 = *(const bf16x8*)&Plds[wave][0][l15 * LDK + 32 * s2 + quad * 8];
      pb1 = *(const bf16x8*)&Plds[wave][1][l15 * LDK + 32 * s2 + quad * 8];
      #pragma unroll
      for (int t = 0; t < 4; ++t) {
        const int d = 16 * t + l15;
        bf16x8 va = *(const bf16x8*)&Vb[d * LDK + (((4 * s2 + quad) ^ vswz_m(d)) << 3)];
        if (f0act)
          ot[0][t] = __builtin_amdgcn_mfma_f32_16x16x32_bf16(va, pb0, ot[0][t], 0, 0, 0);
        ot[1][t] = __builtin_amdgcn_mfma_f32_16x16x32_bf16(va, pb1, ot[1][t], 0, 0, 0);
      }
    }
  }

  // ---- epilogue: O
  #pragma unroll
  for (int f = 0; f < 2; ++f) {
    float inv = 1.0f / lrun[f];
    float* orow = out + base + (qbase + 64 * f + wave * 16 + l15) * Ddim + 4 * quad;
    #pragma unroll
    for (int t = 0; t < 4; ++t) {
      f32x4 o4;
      o4.x = ot[f][t][0] * inv; o4.y = ot[f][t][1] * inv;
      o4.z = ot[f][t][2] * inv; o4.w = ot[f][t][3] * inv;
      *(f32x4*)(orow + 16 * t) = o4;
    }
  }

  // ---- fill remainder: chunks not covered in-loop (light-compute blocks
  // finish early and stream these while heavy partners still compute)
  for (int c = jmax + 1; c < NCHUNK; ++c) {
    f32x4* zp = zbase + c * FCHUNK + tid;
    #pragma unroll
    for (int i = 0; i < FCHUNK / 256; ++i)
      __builtin_nontemporal_store(z4, zp + i * 256);
  }
}

extern "C" void kernel_launch(void* const* d_in, const int* in_sizes, int n_in,
                              void* d_out, int out_size, void* d_ws, size_t ws_size,
                              hipStream_t stream) {
  const float* q = (const float*)d_in[0];
  const float* k = (const float*)d_in[1];
  const float* v = (const float*)d_in[2];
  float* out = (float*)d_out;
  dim3 grid(BHn * STiles);   // 512 blocks: 2/CU, balanced pairs
  flash_causal_kernel<<<grid, dim3(256), 0, stream>>>(q, k, v, out);
}

// Round 10
// 602.863 us; speedup vs baseline: 1.2391x; 1.0061x over previous
//
#include <hip/hip_runtime.h>

// TurboFlashAttention: causal B=2,H=16,S=2048,D=64 fp32 + 512MB zero placeholder.
// R10 = R9 with PLAIN fill stores (not nontemporal). Theory: vmcnt retires in
// order, and the barrier's s_waitcnt vmcnt(0) had to drain NT stores to HBM
// (~900cyc) every iteration; plain stores ack at L2 (~200cyc) and are fully
// drained by compute time. Flash core unchanged: dbuf LDS, 1 barrier/iter,
// swizzled V^T, balanced CU pairs, fill interleaved 32KB/iter.

typedef __bf16 bf16x8 __attribute__((ext_vector_type(8)));
typedef float f32x4 __attribute__((ext_vector_type(4)));

#define LOG2E 1.44269504088896340736f

__device__ __forceinline__ unsigned short f2bf(float f) {
  unsigned int u = __float_as_uint(f);
  u += 0x7fffu + ((u >> 16) & 1u);   // RNE
  return (unsigned short)(u >> 16);
}

constexpr int Sdim = 2048, Ddim = 64, BHn = 32;
constexpr int STiles = 16;                   // 128-row q-supertiles
constexpr int LDK = 72;                      // LDS leading-dim pad (shorts)
constexpr int OUT0 = BHn * Sdim * Ddim;      // output-region floats
constexpr int FCHUNK = 2048;                 // f32x4 per fill chunk (32KB)
constexpr int NCHUNK = 32;                   // chunks per block (1MB total)

__device__ __forceinline__ int vswz_m(int d) { return ((d >> 2) ^ (d >> 5)) & 7; }

__global__ __launch_bounds__(256, 2)
void flash_causal_kernel(const float* __restrict__ Q, const float* __restrict__ K,
                         const float* __restrict__ V, float* __restrict__ out) {
  __shared__ unsigned short Klds[2][64 * LDK];      // K tile [kn][d]
  __shared__ unsigned short Vlds[2][64 * LDK];      // V^T tile [d][kn^swz]
  __shared__ unsigned short Plds[4][2][16 * LDK];   // per-wave, per-frag P^T

  const int tid  = threadIdx.x;
  const int wave = tid >> 6;
  const int lane = tid & 63;
  const int quad = lane >> 4;
  const int l15  = lane & 15;

  const int bh = blockIdx.x & (BHn - 1);
  const int g  = (int)(blockIdx.x >> 5);                 // 0..15
  // Blocks i and i+256 co-resident on one CU -> pair (g, g+8): s-pair sums 15
  // (iteration counts sum to 34) for uniform per-CU compute load.
  const int s  = (g < 8) ? g : (23 - g);
  const int jmax = 2 * s + 1;

  const int base  = bh * Sdim * Ddim;
  const int qbase = s * 128;

  // fill region for this block: 1MB, stored as 32 chunks of 32KB
  f32x4* zbase = (f32x4*)(out + OUT0) + (size_t)blockIdx.x * (FCHUNK * NCHUNK);
  const f32x4 z4 = (f32x4){0.f, 0.f, 0.f, 0.f};

  // ---- Q fragments (B-operand), scale 1/8 folded. frag f: rows qbase+64f+16w.
  bf16x8 aq[2][2];
  #pragma unroll
  for (int f = 0; f < 2; ++f) {
    const float* qp = Q + base + (qbase + 64 * f + wave * 16 + l15) * Ddim + quad * 8;
    #pragma unroll
    for (int s2 = 0; s2 < 2; ++s2) {
      float4 a = *(const float4*)(qp + 32 * s2);
      float4 b = *(const float4*)(qp + 32 * s2 + 4);
      union { unsigned short u[8]; bf16x8 v; } u;
      u.u[0] = f2bf(a.x * 0.125f); u.u[1] = f2bf(a.y * 0.125f);
      u.u[2] = f2bf(a.z * 0.125f); u.u[3] = f2bf(a.w * 0.125f);
      u.u[4] = f2bf(b.x * 0.125f); u.u[5] = f2bf(b.y * 0.125f);
      u.u[6] = f2bf(b.z * 0.125f); u.u[7] = f2bf(b.w * 0.125f);
      aq[f][s2] = u.v;
    }
  }

  f32x4 ot[2][4];
  #pragma unroll
  for (int f = 0; f < 2; ++f)
    #pragma unroll
    for (int t = 0; t < 4; ++t) ot[f][t] = (f32x4){0.f, 0.f, 0.f, 0.f};
  float mrun[2] = {-__builtin_inff(), -__builtin_inff()};
  float lrun[2] = {0.f, 0.f};

  const float4* kg4 = (const float4*)(K + base);
  const float4* vg4 = (const float4*)(V + base);
  float4 kf[4], vf[4];

  auto ldtile = [&](int j) {
    const float4* kp = kg4 + j * 1024;
    const float4* vp = vg4 + j * 1024;
    #pragma unroll
    for (int i = 0; i < 4; ++i) { kf[i] = kp[i * 256 + tid]; vf[i] = vp[i * 256 + tid]; }
  };
  auto stage = [&](int buf) {
    #pragma unroll
    for (int i = 0; i < 4; ++i) {
      int lin = i * 256 + tid;
      int row = lin >> 4;
      int c4  = (lin & 15) << 2;
      uint2 t2;
      t2.x = (unsigned int)f2bf(kf[i].x) | ((unsigned int)f2bf(kf[i].y) << 16);
      t2.y = (unsigned int)f2bf(kf[i].z) | ((unsigned int)f2bf(kf[i].w) << 16);
      *(uint2*)&Klds[buf][row * LDK + c4] = t2;
      const int sw = vswz_m(c4) << 3;
      Vlds[buf][(c4 + 0) * LDK + (row ^ sw)] = f2bf(vf[i].x);
      Vlds[buf][(c4 + 1) * LDK + (row ^ sw)] = f2bf(vf[i].y);
      Vlds[buf][(c4 + 2) * LDK + (row ^ sw)] = f2bf(vf[i].z);
      Vlds[buf][(c4 + 3) * LDK + (row ^ sw)] = f2bf(vf[i].w);
    }
  };

  // ---- prologue
  ldtile(0); stage(0); ldtile(1);   // jmax >= 1 always

  for (int j = 0; j <= jmax; ++j) {
    __syncthreads();
    if (j < jmax) stage((j + 1) & 1);
    if (j + 2 <= jmax) ldtile(j + 2);

    // ---- interleaved zero-fill: one 32KB chunk per iteration, PLAIN stores
    // (L2-ack drain; NT stores poisoned the barrier's vmcnt(0) in R9)
    if (j < NCHUNK) {
      f32x4* zp = zbase + j * FCHUNK + tid;
      #pragma unroll
      for (int i = 0; i < FCHUNK / 256; ++i)
        zp[i * 256] = z4;
    }

    const unsigned short* Kb = Klds[j & 1];
    const unsigned short* Vb = Vlds[j & 1];
    const bool f0act = (j <= 2 * s);   // frag0 has no columns at j == jmax

    // ---- S^T for both frags; K fragment read once, used twice
    f32x4 sc[2][4];
    #pragma unroll
    for (int f = 0; f < 2; ++f)
      #pragma unroll
      for (int t = 0; t < 4; ++t) sc[f][t] = (f32x4){0.f, 0.f, 0.f, 0.f};
    #pragma unroll
    for (int s2 = 0; s2 < 2; ++s2) {
      #pragma unroll
      for (int t = 0; t < 4; ++t) {
        bf16x8 ka = *(const bf16x8*)&Kb[(16 * t + l15) * LDK + 32 * s2 + quad * 8];
        sc[0][t] = __builtin_amdgcn_mfma_f32_16x16x32_bf16(ka, aq[0][s2], sc[0][t], 0, 0, 0);
        sc[1][t] = __builtin_amdgcn_mfma_f32_16x16x32_bf16(ka, aq[1][s2], sc[1][t], 0, 0, 0);
      }
    }

    // ---- causal diagonal masks (frag f diag at j == 2s+f)
    #pragma unroll
    for (int f = 0; f < 2; ++f) {
      if (j == 2 * s + f) {
        const int qml = wave * 16 + l15;
        #pragma unroll
        for (int t = 0; t < 4; ++t)
          #pragma unroll
          for (int r = 0; r < 4; ++r)
            if (16 * t + 4 * quad + r > qml) sc[f][t][r] = -__builtin_inff();
      }
    }

    // ---- online softmax + P write (per frag; frag0 idle on final odd iter)
    #pragma unroll
    for (int f = 0; f < 2; ++f) {
      if (f == 0 && !f0act) continue;
      float mx = sc[f][0][0];
      #pragma unroll
      for (int t = 0; t < 4; ++t)
        #pragma unroll
        for (int r = 0; r < 4; ++r) mx = fmaxf(mx, sc[f][t][r]);
      mx = fmaxf(mx, __shfl_xor(mx, 16));
      mx = fmaxf(mx, __shfl_xor(mx, 32));
      float mn    = fmaxf(mrun[f], mx);
      float alpha = __builtin_amdgcn_exp2f((mrun[f] - mn) * LOG2E);
      float msc   = mn * LOG2E;
      mrun[f] = mn;
      float rs = 0.f;
      #pragma unroll
      for (int t = 0; t < 4; ++t)
        #pragma unroll
        for (int r = 0; r < 4; ++r) {
          float p = __builtin_amdgcn_exp2f(fmaf(sc[f][t][r], LOG2E, -msc));
          sc[f][t][r] = p;
          rs += p;
        }
      rs += __shfl_xor(rs, 16);
      rs += __shfl_xor(rs, 32);
      lrun[f] = lrun[f] * alpha + rs;
      #pragma unroll
      for (int t = 0; t < 4; ++t)
        #pragma unroll
        for (int r = 0; r < 4; ++r) ot[f][t][r] *= alpha;
      #pragma unroll
      for (int t = 0; t < 4; ++t) {
        uint2 pw;
        pw.x = (unsigned int)f2bf(sc[f][t][0]) | ((unsigned int)f2bf(sc[f][t][1]) << 16);
        pw.y = (unsigned int)f2bf(sc[f][t][2]) | ((unsigned int)f2bf(sc[f][t][3]) << 16);
        *(uint2*)&Plds[wave][f][l15 * LDK + 16 * t + 4 * quad] = pw;
      }
    }

    // ---- O^T += V^T * P^T; V fragment read once, used for both frags
    #pragma unroll
    for (int s2 = 0; s2 < 2; ++s2) {
      bf16x8 pb0, pb1;
      if (f0act) pb0 = *(const bf16x8*)&Plds[wave][0][l15 * LDK + 32 * s2 + quad * 8];
      pb1 = *(const bf16x8*)&Plds[wave][1][l15 * LDK + 32 * s2 + quad * 8];
      #pragma unroll
      for (int t = 0; t < 4; ++t) {
        const int d = 16 * t + l15;
        bf16x8 va = *(const bf16x8*)&Vb[d * LDK + (((4 * s2 + quad) ^ vswz_m(d)) << 3)];
        if (f0act)
          ot[0][t] = __builtin_amdgcn_mfma_f32_16x16x32_bf16(va, pb0, ot[0][t], 0, 0, 0);
        ot[1][t] = __builtin_amdgcn_mfma_f32_16x16x32_bf16(va, pb1, ot[1][t], 0, 0, 0);
      }
    }
  }

  // ---- epilogue: O
  #pragma unroll
  for (int f = 0; f < 2; ++f) {
    float inv = 1.0f / lrun[f];
    float* orow = out + base + (qbase + 64 * f + wave * 16 + l15) * Ddim + 4 * quad;
    #pragma unroll
    for (int t = 0; t < 4; ++t) {
      f32x4 o4;
      o4.x = ot[f][t][0] * inv; o4.y = ot[f][t][1] * inv;
      o4.z = ot[f][t][2] * inv; o4.w = ot[f][t][3] * inv;
      *(f32x4*)(orow + 16 * t) = o4;
    }
  }

  // ---- fill remainder: chunks not covered in-loop (light-compute blocks
  // finish early and stream these while heavy partners still compute)
  for (int c = jmax + 1; c < NCHUNK; ++c) {
    f32x4* zp = zbase + c * FCHUNK + tid;
    #pragma unroll
    for (int i = 0; i < FCHUNK / 256; ++i)
      zp[i * 256] = z4;
  }
}

extern "C" void kernel_launch(void* const* d_in, const int* in_sizes, int n_in,
                              void* d_out, int out_size, void* d_ws, size_t ws_size,
                              hipStream_t stream) {
  const float* q = (const float*)d_in[0];
  const float* k = (const float*)d_in[1];
  const float* v = (const float*)d_in[2];
  float* out = (float*)d_out;
  dim3 grid(BHn * STiles);   // 512 blocks: 2/CU, balanced pairs
  flash_causal_kernel<<<grid, dim3(256), 0, stream>>>(q, k, v, out);
}